// Round 5
// baseline (723.262 us; speedup 1.0000x reference)
//
#include <hip/hip_runtime.h>

// ---------------------------------------------------------------------------
// Algebraic collapse: the scan is linear & batch-independent.
//   m_{t+1} = A m_t + beta,  A[(j,e),(i,d)] = gate[i,j]*W[i,j,e,d]
//   out = inp @ Weff^T + beff,  Weff = Wpost * S * Wpre,
//   S = (A^10)[block15, block0],  c = (sum_{k<10} A^k beta)[block15]
// Round 7: split-K reduce fused into step_kernel ("last block per n-tile
// reduces" with device-scope fences + per-step atomic tickets). Kills the
// 8 reduce dispatches + their full-grid drains, and step 9 writes St/gv
// fp32 directly (extract_Sc gone). Dispatches: 22 -> 13.
// Step GEMM keeps round-6's depth-3 register pipeline, KS=8, 512 blocks.
// ---------------------------------------------------------------------------

typedef __bf16 bf16x8 __attribute__((ext_vector_type(8)));
typedef float f32x4 __attribute__((ext_vector_type(4)));

__device__ __forceinline__ unsigned short f2bf(float x) {
  unsigned int u = __float_as_uint(x);
  u += 0x7FFFu + ((u >> 16) & 1u);   // round-to-nearest-even
  return (unsigned short)(u >> 16);
}
__device__ __forceinline__ float bf2f(unsigned short s) {
  return __uint_as_float(((unsigned int)s) << 16);
}
__device__ __forceinline__ bf16x8 ldg8(const unsigned short* p) {
  return __builtin_bit_cast(bf16x8, *(const uint4*)p);
}
__device__ __forceinline__ f32x4 mfma16(bf16x8 a, bf16x8 b, f32x4 c) {
  return __builtin_amdgcn_mfma_f32_16x16x32_bf16(a, b, c, 0, 0, 0);
}

#define ND 2048   // num*dim
#define MT 144    // padded iterate rows (129 used: 128 propagator + 1 bias)
#define KS 8      // split-K chunks (256 k each)

// ---------------------------------------------------------------------------
// Phase 0 (fused): build A hi/lo, build Q1 (t=1 iterate, exact) + beta,
// split inp -> hi/lo, zero split-K tickets. All independent, grid-strided.
// ---------------------------------------------------------------------------
__global__ __launch_bounds__(256) void build_all(
    const float* __restrict__ W, const float* __restrict__ life,
    const float* __restrict__ bl, const float* __restrict__ inp,
    unsigned short* __restrict__ Ahi, unsigned short* __restrict__ Alo,
    unsigned short* __restrict__ Qhi, unsigned short* __restrict__ Qlo,
    float* __restrict__ beta,
    unsigned short* __restrict__ Ihi, unsigned short* __restrict__ Ilo,
    int* __restrict__ cnt) {
  const int tid = blockIdx.x * 256 + threadIdx.x;
  const int NT = gridDim.x * 256;

  // Job D: zero the 9*64 split-K tickets (fresh every graph replay)
  if (tid < 576) cnt[tid] = 0;

  // Job A: A_hi/A_lo [2048x2048] row-major (n=(j,e), k=(i,d)), 8 elems/item
  for (int item = tid; item < (ND * ND) / 8; item += NT) {
    int base = item * 8;
    int n = base >> 11, k = base & 2047;
    int j = n >> 7, i = k >> 7;
    float gval = life[i * 16 + j];
    float gate = gval > 0.f ? gval : 0.f;
    const float* src = W + ((i * 16 + j) * 16384 + (n & 127) * 128 + (k & 127));
    float4 x = *(const float4*)src, y = *(const float4*)(src + 4);
    float vals[8] = {x.x, x.y, x.z, x.w, y.x, y.y, y.z, y.w};
    union { unsigned short u[8]; uint4 v; } ph, pl;
#pragma unroll
    for (int q = 0; q < 8; ++q) {
      float v = gate * vals[q];
      unsigned short h = f2bf(v);
      ph.u[q] = h;
      pl.u[q] = f2bf(v - bf2f(h));
    }
    *(uint4*)(Ahi + base) = ph.v;
    *(uint4*)(Alo + base) = pl.v;
  }

  // Job B: Q1[c=d][n=(j,e)] = gate[0,j]*W[0,j,e,d]; row 128 = beta; rest 0.
  for (int item = tid; item < MT * ND; item += NT) {
    int m = item >> 11, n = item & 2047;
    int j = n >> 7, e = n & 127;
    unsigned short hh = 0, ll = 0;
    if (m < 128) {
      float gval = life[j];                         // i = 0
      float gate = gval > 0.f ? gval : 0.f;
      float v = gate * W[j * 16384 + e * 128 + m];
      hh = f2bf(v); ll = f2bf(v - bf2f(hh));
    } else if (m == 128) {
      float s = 0.f;
#pragma unroll
      for (int i = 0; i < 16; ++i) {
        float gval = life[i * 16 + j];
        float gate = gval > 0.f ? gval : 0.f;
        s += gate * bl[(i * 16 + j) * 128 + e];
      }
      beta[n] = s;
      hh = f2bf(s); ll = f2bf(s - bf2f(hh));
    }
    Qhi[item] = hh;
    Qlo[item] = ll;
  }

  // Job C: split inp -> hi/lo bf16, 8 elems/item
  for (int item = tid; item < (4096 * 512) / 8; item += NT) {
    int base = item * 8;
    float4 x = *(const float4*)(inp + base), y = *(const float4*)(inp + base + 4);
    float vals[8] = {x.x, x.y, x.z, x.w, y.x, y.y, y.z, y.w};
    union { unsigned short u[8]; uint4 v; } ph, pl;
#pragma unroll
    for (int q = 0; q < 8; ++q) {
      unsigned short h = f2bf(vals[q]);
      ph.u[q] = h;
      pl.u[q] = f2bf(vals[q] - bf2f(h));
    }
    *(uint4*)(Ihi + base) = ph.v;
    *(uint4*)(Ilo + base) = pl.v;
  }
}

// ---------------------------------------------------------------------------
// One step with fused split-K reduction.
// Grid (nb, kc): nb over 32-wide n-tiles, kc over 8 k-chunks of 256.
// Block = 3 waves; wave g owns m-rows [g*48, g*48+48) (3 m-tiles x 2 n-tiles).
// Depth-3 register pipeline (round-6 win). After writing its partial, each
// block takes a ticket on cnt[nb]; the KS-th block reduces all partials for
// this n-tile, adds beta, and writes bf16-split output (or, on the last
// step, St/gv in fp32). Device-scope fences per §G16.
// ---------------------------------------------------------------------------
#define DECL_SET(s) \
  bf16x8 b0h##s, b0l##s, b1h##s, b1l##s, a0h##s, a0l##s, a1h##s, a1l##s, \
      a2h##s, a2l##s;

#define LOADS(s, ko)                                                         \
  b0h##s = ldg8(pB0h + (ko)); b0l##s = ldg8(pB0l + (ko));                    \
  b1h##s = ldg8(pB1h + (ko)); b1l##s = ldg8(pB1l + (ko));                    \
  a0h##s = ldg8(pA0h + (ko)); a0l##s = ldg8(pA0l + (ko));                    \
  a1h##s = ldg8(pA0h + 16 * ND + (ko)); a1l##s = ldg8(pA0l + 16 * ND + (ko)); \
  a2h##s = ldg8(pA0h + 32 * ND + (ko)); a2l##s = ldg8(pA0l + 32 * ND + (ko));

#define MFMAS(s)                                      \
  acc[0][0] = mfma16(a0h##s, b0h##s, acc[0][0]);      \
  acc[0][0] = mfma16(a0l##s, b0h##s, acc[0][0]);      \
  acc[0][0] = mfma16(a0h##s, b0l##s, acc[0][0]);      \
  acc[1][0] = mfma16(a1h##s, b0h##s, acc[1][0]);      \
  acc[1][0] = mfma16(a1l##s, b0h##s, acc[1][0]);      \
  acc[1][0] = mfma16(a1h##s, b0l##s, acc[1][0]);      \
  acc[2][0] = mfma16(a2h##s, b0h##s, acc[2][0]);      \
  acc[2][0] = mfma16(a2l##s, b0h##s, acc[2][0]);      \
  acc[2][0] = mfma16(a2h##s, b0l##s, acc[2][0]);      \
  acc[0][1] = mfma16(a0h##s, b1h##s, acc[0][1]);      \
  acc[0][1] = mfma16(a0l##s, b1h##s, acc[0][1]);      \
  acc[0][1] = mfma16(a0h##s, b1l##s, acc[0][1]);      \
  acc[1][1] = mfma16(a1h##s, b1h##s, acc[1][1]);      \
  acc[1][1] = mfma16(a1l##s, b1h##s, acc[1][1]);      \
  acc[1][1] = mfma16(a1h##s, b1l##s, acc[1][1]);      \
  acc[2][1] = mfma16(a2h##s, b1h##s, acc[2][1]);      \
  acc[2][1] = mfma16(a2l##s, b1h##s, acc[2][1]);      \
  acc[2][1] = mfma16(a2h##s, b1l##s, acc[2][1]);

__global__ __launch_bounds__(192, 2) void step_kernel(
    const unsigned short* __restrict__ Ahi, const unsigned short* __restrict__ Alo,
    const unsigned short* __restrict__ Qhi, const unsigned short* __restrict__ Qlo,
    float* __restrict__ P, int nb_off,
    int* __restrict__ cnt, const float* __restrict__ beta,
    unsigned short* __restrict__ Ohi, unsigned short* __restrict__ Olo,
    float* __restrict__ St, float* __restrict__ gv, int last) {
  const int t = threadIdx.x;
  const int g = t >> 6, lane = t & 63;
  const int r16 = lane & 15, q = lane >> 4;
  const int nb = blockIdx.x + nb_off;
  const int kc = blockIdx.y;
  const int kbase = kc * 256 + q * 8;
  const int n0 = nb * 32;
  const int PSTR = MT * ND;

  const unsigned short* pB0h = Ahi + (n0 + r16) * ND + kbase;      // A rows (B-op)
  const unsigned short* pB0l = Alo + (n0 + r16) * ND + kbase;
  const unsigned short* pB1h = pB0h + 16 * ND;
  const unsigned short* pB1l = pB0l + 16 * ND;
  const int m0 = g * 48 + r16;
  const unsigned short* pA0h = Qhi + m0 * ND + kbase;              // Q rows (A-op)
  const unsigned short* pA0l = Qlo + m0 * ND + kbase;

  f32x4 acc[3][2];
#pragma unroll
  for (int mt = 0; mt < 3; ++mt)
#pragma unroll
    for (int nt = 0; nt < 2; ++nt) acc[mt][nt] = (f32x4){0.f, 0.f, 0.f, 0.f};

  DECL_SET(0) DECL_SET(1) DECL_SET(2)

  // 8 k-iterations of 32, pipelined depth-3 (sets cycle 0,1,2,0,1,2,0,1)
  LOADS(0, 0)
  LOADS(1, 32)
  LOADS(2, 64)   MFMAS(0)
  LOADS(0, 96)   MFMAS(1)
  LOADS(1, 128)  MFMAS(2)
  LOADS(2, 160)  MFMAS(0)
  LOADS(0, 192)  MFMAS(1)
  LOADS(1, 224)  MFMAS(2)
  MFMAS(0)
  MFMAS(1)

  float* Pk = P + kc * PSTR;
#pragma unroll
  for (int mt = 0; mt < 3; ++mt)
#pragma unroll
    for (int nt = 0; nt < 2; ++nt) {
      int mbase = g * 48 + mt * 16 + q * 4;
      int n = n0 + nt * 16 + r16;
#pragma unroll
      for (int r = 0; r < 4; ++r)
        Pk[(mbase + r) * ND + n] = acc[mt][nt][r];
    }

  // ---- fused split-K reduction: last block for this n-tile reduces ----
  __shared__ int amLast;
  __threadfence();                       // release: publish our partial
  if (t == 0) {
    int old = atomicAdd(&cnt[nb], 1);
    amLast = (old == KS - 1);
  }
  __syncthreads();
  if (!amLast) return;
  __threadfence();                       // acquire: see all partials

  for (int item = t; item < MT * 8; item += 192) {
    int m = item >> 3;
    int n = n0 + (item & 7) * 4;
    int idx = m * ND + n;
    float v0 = 0.f, v1 = 0.f, v2 = 0.f, v3 = 0.f;
#pragma unroll
    for (int c = 0; c < KS; ++c) {
      float4 s = *(const float4*)(P + c * PSTR + idx);
      v0 += s.x; v1 += s.y; v2 += s.z; v3 += s.w;
    }
    if (m == 128) {
      float4 b4 = *(const float4*)(beta + n);
      v0 += b4.x; v1 += b4.y; v2 += b4.z; v3 += b4.w;
    }
    if (!last) {
      union { unsigned short u[4]; uint2 d; } h, l;
      float vv[4] = {v0, v1, v2, v3};
#pragma unroll
      for (int i = 0; i < 4; ++i) {
        unsigned short hh = f2bf(vv[i]);
        h.u[i] = hh;
        l.u[i] = f2bf(vv[i] - bf2f(hh));
      }
      *(uint2*)(Ohi + idx) = h.d;
      *(uint2*)(Olo + idx) = l.d;
    } else {
      int col = n - 1920;                // St[d][e] = Q10[d][1920+e], fp32
      if (m < 128) {
        float4 o = {v0, v1, v2, v3};
        *(float4*)(St + m * 128 + col) = o;
      } else if (m == 128) {
        float4 o = {v0, v1, v2, v3};     // gv = c-vector (beta added above)
        *(float4*)(gv + col) = o;
      }
    }
  }
}

// ---------------------------------------------------------------------------
// Tail (2 wide kernels, fp32-exact S path):
//   tail_T1g:   T1[e,ic] = sum_d St[d][e]*Wpre[d,ic];  g[e] = c[e]+St[:,e]·bpre
//   tail_Weff:  Weff[o,ic] = sum_e Wpost[o,e]*T1[e,ic] -> split bf16;
//               beff[o] = bpost[o] + Wpost[o,:]·g
// ---------------------------------------------------------------------------
__global__ __launch_bounds__(256) void tail_T1g(
    const float* __restrict__ St, const float* __restrict__ Wpre,
    const float* __restrict__ bpre, float* __restrict__ T1,
    float* __restrict__ gv) {
  int t = blockIdx.x * 256 + threadIdx.x;
  if (t < 65536) {
    int e = t >> 9, ic = t & 511;
    float s = 0.f;
    for (int d = 0; d < 128; ++d) s += St[d * 128 + e] * Wpre[d * 512 + ic];
    T1[t] = s;
  } else if (t < 65664) {
    int e = t - 65536;
    float s = gv[e];
    for (int d = 0; d < 128; ++d) s += St[d * 128 + e] * bpre[d];
    gv[e] = s;                                   // only this thread touches e
  }
}

__global__ __launch_bounds__(256) void tail_Weff(
    const float* __restrict__ Wpost, const float* __restrict__ T1,
    const float* __restrict__ gv, const float* __restrict__ bpost,
    unsigned short* __restrict__ Whi, unsigned short* __restrict__ Wlo,
    float* __restrict__ beff) {
  int t = blockIdx.x * 256 + threadIdx.x;
  if (t < 262144) {
    int o = t >> 9, ic = t & 511;
    float s = 0.f;
    for (int e = 0; e < 128; ++e) s += Wpost[o * 128 + e] * T1[e * 512 + ic];
    unsigned short h = f2bf(s);
    Whi[t] = h;
    Wlo[t] = f2bf(s - bf2f(h));
  } else if (t < 262656) {
    int o = t - 262144;
    float s = bpost[o];
    for (int e = 0; e < 128; ++e) s += Wpost[o * 128 + e] * gv[e];
    beff[o] = s;
  }
}

// ---------------------------------------------------------------------------
// out[4096,512] = inp @ Weff^T + beff. M=4096,N=512,K=512, split bf16.
// Block tile 64(M) x 128(N): grid (64,4), 4 waves; wave w owns n-cols [32w,32w+32).
// ---------------------------------------------------------------------------
__global__ __launch_bounds__(256) void final_gemm(
    const unsigned short* __restrict__ Ihi, const unsigned short* __restrict__ Ilo,
    const unsigned short* __restrict__ Whi, const unsigned short* __restrict__ Wlo,
    const float* __restrict__ beff, float* __restrict__ out) {
  __shared__ __align__(16) unsigned short Is_hi[64][40], Is_lo[64][40];
  __shared__ __align__(16) unsigned short Ws_hi[128][40], Ws_lo[128][40];
  const int t = threadIdx.x;
  const int mb = blockIdx.x, nb = blockIdx.y;
  const int w = t >> 6, lane = t & 63;
  const int r16 = lane & 15, q = lane >> 4;

  f32x4 acc[4][2];
#pragma unroll
  for (int x = 0; x < 4; ++x)
#pragma unroll
    for (int b = 0; b < 2; ++b) acc[x][b] = (f32x4){0.f, 0.f, 0.f, 0.f};

  for (int kc = 0; kc < 16; ++kc) {
    const int k0 = kc * 32;
#pragma unroll
    for (int rpt = 0; rpt < 6; ++rpt) {
      int slot = t + rpt * 256;
      if (slot < 512) {
        int arr = slot >> 8, s = slot & 255;
        int row = s >> 2, off = (s & 3) * 8;
        const unsigned short* src = arr ? Ilo : Ihi;
        unsigned short* dst = arr ? &Is_lo[row][off] : &Is_hi[row][off];
        *(uint4*)dst = *(const uint4*)(src + (mb * 64 + row) * 512 + k0 + off);
      } else {
        int s = slot - 512;
        int arr = s >> 9, s2 = s & 511;
        int row = s2 >> 2, off = (s2 & 3) * 8;
        const unsigned short* src = arr ? Wlo : Whi;
        unsigned short* dst = arr ? &Ws_lo[row][off] : &Ws_hi[row][off];
        *(uint4*)dst = *(const uint4*)(src + (nb * 128 + row) * 512 + k0 + off);
      }
    }
    __syncthreads();

    bf16x8 bh0 = __builtin_bit_cast(bf16x8, *(const uint4*)&Ws_hi[w * 32 + r16][q * 8]);
    bf16x8 bl0 = __builtin_bit_cast(bf16x8, *(const uint4*)&Ws_lo[w * 32 + r16][q * 8]);
    bf16x8 bh1 = __builtin_bit_cast(bf16x8, *(const uint4*)&Ws_hi[w * 32 + 16 + r16][q * 8]);
    bf16x8 bl1 = __builtin_bit_cast(bf16x8, *(const uint4*)&Ws_lo[w * 32 + 16 + r16][q * 8]);
#pragma unroll
    for (int mt = 0; mt < 4; ++mt) {
      bf16x8 ah = __builtin_bit_cast(bf16x8, *(const uint4*)&Is_hi[mt * 16 + r16][q * 8]);
      bf16x8 al = __builtin_bit_cast(bf16x8, *(const uint4*)&Is_lo[mt * 16 + r16][q * 8]);
      acc[mt][0] = mfma16(ah, bh0, acc[mt][0]);
      acc[mt][0] = mfma16(al, bh0, acc[mt][0]);
      acc[mt][0] = mfma16(ah, bl0, acc[mt][0]);
      acc[mt][1] = mfma16(ah, bh1, acc[mt][1]);
      acc[mt][1] = mfma16(al, bh1, acc[mt][1]);
      acc[mt][1] = mfma16(ah, bl1, acc[mt][1]);
    }
    __syncthreads();
  }

#pragma unroll
  for (int mt = 0; mt < 4; ++mt)
#pragma unroll
    for (int nt = 0; nt < 2; ++nt) {
      int n = nb * 128 + w * 32 + nt * 16 + r16;
      float bv = beff[n];
#pragma unroll
      for (int r = 0; r < 4; ++r) {
        int m = mb * 64 + mt * 16 + q * 4 + r;
        out[m * 512 + n] = acc[mt][nt][r] + bv;
      }
    }
}

extern "C" void kernel_launch(void* const* d_in, const int* in_sizes, int n_in,
                              void* d_out, int out_size, void* d_ws, size_t ws_size,
                              hipStream_t stream) {
  const float* inp   = (const float*)d_in[0];
  const float* Wpre  = (const float*)d_in[1];
  const float* bpre  = (const float*)d_in[2];
  const float* W     = (const float*)d_in[3];
  const float* bl    = (const float*)d_in[4];
  const float* life  = (const float*)d_in[5];
  const float* Wpost = (const float*)d_in[6];
  const float* bpost = (const float*)d_in[7];
  float* out = (float*)d_out;

  char* p = (char*)d_ws;
  auto alloc = [&](size_t bytes) {
    char* r = p;
    p += (bytes + 255) & ~(size_t)255;
    return r;
  };
  unsigned short* Ahi  = (unsigned short*)alloc((size_t)ND * ND * 2);
  unsigned short* Alo  = (unsigned short*)alloc((size_t)ND * ND * 2);
  unsigned short* QAhi = (unsigned short*)alloc((size_t)MT * ND * 2);
  unsigned short* QAlo = (unsigned short*)alloc((size_t)MT * ND * 2);
  unsigned short* QBhi = (unsigned short*)alloc((size_t)MT * ND * 2);
  unsigned short* QBlo = (unsigned short*)alloc((size_t)MT * ND * 2);
  float* beta = (float*)alloc(ND * 4);
  float* P    = (float*)alloc((size_t)KS * MT * ND * 4);
  int*   cnt  = (int*)alloc(9 * 64 * 4);
  float* St   = (float*)alloc(128 * 128 * 4);
  float* gv   = (float*)alloc(128 * 4);
  float* T1   = (float*)alloc(128 * 512 * 4);
  float* beff = (float*)alloc(512 * 4);
  unsigned short* Whi = (unsigned short*)alloc(512 * 512 * 2);
  unsigned short* Wlo = (unsigned short*)alloc(512 * 512 * 2);
  unsigned short* Ihi = (unsigned short*)alloc((size_t)4096 * 512 * 2);
  unsigned short* Ilo = (unsigned short*)alloc((size_t)4096 * 512 * 2);

  build_all<<<1024, 256, 0, stream>>>(W, life, bl, inp, Ahi, Alo, QAhi, QAlo,
                                      beta, Ihi, Ilo, cnt);

  // steps t=2..10: 8 full multiplies + 1 restricted to n in [1920,2048)
  const unsigned short *qh = QAhi, *ql = QAlo;
  unsigned short *oh = QBhi, *ol = QBlo;
  for (int i = 1; i <= 9; ++i) {
    int* cs = cnt + (i - 1) * 64;
    if (i < 9) {
      step_kernel<<<dim3(64, KS), 192, 0, stream>>>(
          Ahi, Alo, qh, ql, P, 0, cs, beta, oh, ol, St, gv, 0);
      const unsigned short* th = qh; qh = oh; oh = (unsigned short*)th;
      const unsigned short* tl = ql; ql = ol; ol = (unsigned short*)tl;
    } else {
      step_kernel<<<dim3(4, KS), 192, 0, stream>>>(
          Ahi, Alo, qh, ql, P, 60, cs, beta, oh, ol, St, gv, 1);
    }
  }

  tail_T1g<<<257, 256, 0, stream>>>(St, Wpre, bpre, T1, gv);
  tail_Weff<<<1026, 256, 0, stream>>>(Wpost, T1, gv, bpost, Whi, Wlo, beff);
  final_gemm<<<dim3(64, 4), 256, 0, stream>>>(Ihi, Ilo, Whi, Wlo, beff, out);
}

// Round 6
// 286.033 us; speedup vs baseline: 2.5286x; 2.5286x over previous
//
#include <hip/hip_runtime.h>

// ---------------------------------------------------------------------------
// Algebraic collapse: the scan is linear & batch-independent.
//   m_{t+1} = A m_t + beta,  A[(j,e),(i,d)] = gate[i,j]*W[i,j,e,d]
//   out = inp @ Weff^T + beff,  Weff = Wpost * S * Wpre,
//   S = (A^10)[block15, block0],  c = (sum_{k<10} A^k beta)[block15]
// Round 8: revert round-7 fences (device-scope __threadfence = L2 writeback
// per block on non-coherent XCDs -> 72us/step). Back to round-6 structure
// (310us verified: separate reduce dispatches, KS=8). New: step_kernel
// stages its A-tile (32KB) into LDS via global_load_lds width=16 (no VGPR
// cost, one vmcnt drain per block instead of 8 per-iter load stalls), with
// XOR-swizzled source + swizzled ds_read (2-way conflicts = free). Q loads
// stay direct-global (L2-hot). Dispatches: 22.
// ---------------------------------------------------------------------------

typedef __bf16 bf16x8 __attribute__((ext_vector_type(8)));
typedef float f32x4 __attribute__((ext_vector_type(4)));
typedef __attribute__((address_space(3))) unsigned int lds_u32;
typedef const __attribute__((address_space(1))) unsigned int glb_u32;

__device__ __forceinline__ unsigned short f2bf(float x) {
  unsigned int u = __float_as_uint(x);
  u += 0x7FFFu + ((u >> 16) & 1u);   // round-to-nearest-even
  return (unsigned short)(u >> 16);
}
__device__ __forceinline__ float bf2f(unsigned short s) {
  return __uint_as_float(((unsigned int)s) << 16);
}
__device__ __forceinline__ bf16x8 ldg8(const unsigned short* p) {
  return __builtin_bit_cast(bf16x8, *(const uint4*)p);
}
__device__ __forceinline__ f32x4 mfma16(bf16x8 a, bf16x8 b, f32x4 c) {
  return __builtin_amdgcn_mfma_f32_16x16x32_bf16(a, b, c, 0, 0, 0);
}

#define ND 2048   // num*dim
#define MT 144    // padded iterate rows (129 used: 128 propagator + 1 bias)
#define KS 8      // split-K chunks (256 k each)

// ---------------------------------------------------------------------------
// Phase 0 (fused): build A hi/lo, build Q1 (t=1 iterate, exact) + beta,
// split inp -> hi/lo. All independent jobs, grid-strided.
// ---------------------------------------------------------------------------
__global__ __launch_bounds__(256) void build_all(
    const float* __restrict__ W, const float* __restrict__ life,
    const float* __restrict__ bl, const float* __restrict__ inp,
    unsigned short* __restrict__ Ahi, unsigned short* __restrict__ Alo,
    unsigned short* __restrict__ Qhi, unsigned short* __restrict__ Qlo,
    float* __restrict__ beta,
    unsigned short* __restrict__ Ihi, unsigned short* __restrict__ Ilo) {
  const int tid = blockIdx.x * 256 + threadIdx.x;
  const int NT = gridDim.x * 256;

  // Job A: A_hi/A_lo [2048x2048] row-major (n=(j,e), k=(i,d)), 8 elems/item
  for (int item = tid; item < (ND * ND) / 8; item += NT) {
    int base = item * 8;
    int n = base >> 11, k = base & 2047;
    int j = n >> 7, i = k >> 7;
    float gval = life[i * 16 + j];
    float gate = gval > 0.f ? gval : 0.f;
    const float* src = W + ((i * 16 + j) * 16384 + (n & 127) * 128 + (k & 127));
    float4 x = *(const float4*)src, y = *(const float4*)(src + 4);
    float vals[8] = {x.x, x.y, x.z, x.w, y.x, y.y, y.z, y.w};
    union { unsigned short u[8]; uint4 v; } ph, pl;
#pragma unroll
    for (int q = 0; q < 8; ++q) {
      float v = gate * vals[q];
      unsigned short h = f2bf(v);
      ph.u[q] = h;
      pl.u[q] = f2bf(v - bf2f(h));
    }
    *(uint4*)(Ahi + base) = ph.v;
    *(uint4*)(Alo + base) = pl.v;
  }

  // Job B: Q1[c=d][n=(j,e)] = gate[0,j]*W[0,j,e,d]; row 128 = beta; rest 0.
  for (int item = tid; item < MT * ND; item += NT) {
    int m = item >> 11, n = item & 2047;
    int j = n >> 7, e = n & 127;
    unsigned short hh = 0, ll = 0;
    if (m < 128) {
      float gval = life[j];                         // i = 0
      float gate = gval > 0.f ? gval : 0.f;
      float v = gate * W[j * 16384 + e * 128 + m];
      hh = f2bf(v); ll = f2bf(v - bf2f(hh));
    } else if (m == 128) {
      float s = 0.f;
#pragma unroll
      for (int i = 0; i < 16; ++i) {
        float gval = life[i * 16 + j];
        float gate = gval > 0.f ? gval : 0.f;
        s += gate * bl[(i * 16 + j) * 128 + e];
      }
      beta[n] = s;
      hh = f2bf(s); ll = f2bf(s - bf2f(hh));
    }
    Qhi[item] = hh;
    Qlo[item] = ll;
  }

  // Job C: split inp -> hi/lo bf16, 8 elems/item
  for (int item = tid; item < (4096 * 512) / 8; item += NT) {
    int base = item * 8;
    float4 x = *(const float4*)(inp + base), y = *(const float4*)(inp + base + 4);
    float vals[8] = {x.x, x.y, x.z, x.w, y.x, y.y, y.z, y.w};
    union { unsigned short u[8]; uint4 v; } ph, pl;
#pragma unroll
    for (int q = 0; q < 8; ++q) {
      unsigned short h = f2bf(vals[q]);
      ph.u[q] = h;
      pl.u[q] = f2bf(vals[q] - bf2f(h));
    }
    *(uint4*)(Ihi + base) = ph.v;
    *(uint4*)(Ilo + base) = pl.v;
  }
}

// ---------------------------------------------------------------------------
// One step: P[kc][c][n] = sum_{k in chunk} QT[c,k]*A[n,k].
// Grid (nb, kc): nb over 32-wide n-tiles, kc over 8 k-chunks of 256.
// Block = 3 waves; wave g owns m-rows [g*48, g*48+48) (3 m-tiles x 2 n-tiles).
// A-tile (B-operand, 32 rows x 256 k x hi/lo = 32KB) staged to LDS via
// global_load_lds w=16: linear LDS dest + inverse-XOR-swizzled global source;
// ds_read index applies the same XOR (rule: both-sides-or-neither). Row pairs
// 16 apart share (row&7) so one swizzled col index serves all 4 B-frags.
// Q fragments stay direct-global (L2-hot), depth-2 buffered, full unroll.
// ---------------------------------------------------------------------------
__global__ __launch_bounds__(192, 2) void step_kernel(
    const unsigned short* __restrict__ Ahi, const unsigned short* __restrict__ Alo,
    const unsigned short* __restrict__ Qhi, const unsigned short* __restrict__ Qlo,
    float* __restrict__ P, int nb_off) {
  __shared__ __align__(16) unsigned short AS[64][256];  // rows 0-31 hi, 32-63 lo
  const int t = threadIdx.x;
  const int g = t >> 6, lane = t & 63;
  const int r16 = lane & 15, q = lane >> 4;
  const int nb = blockIdx.x + nb_off;
  const int kc = blockIdx.y;
  const int kbase = kc * 256;
  const int n0 = nb * 32;

  // ---- stage A-tile: 2048 16B-slots as 32 chunks of 64; wave g does
  // chunks g, g+3, ... Source col pre-swizzled so the linear LDS write
  // lands data such that read col = c ^ (row&7).
  for (int ch = g; ch < 32; ch += 3) {
    int s = ch * 64 + lane;
    int row = s >> 5;                       // 0..63
    int c16 = (s & 31) ^ (row & 7);         // inverse swizzle on source
    const unsigned short* src =
        (row < 32 ? Ahi + (size_t)(n0 + row) * ND
                  : Alo + (size_t)(n0 + row - 32) * ND) + kbase + c16 * 8;
    __builtin_amdgcn_global_load_lds((glb_u32*)src,
                                     (lds_u32*)(&AS[0][0] + ch * 512), 16, 0, 0);
  }
  __syncthreads();   // compiler emits vmcnt(0) drain before barrier

  const int m0 = g * 48 + r16;
  const unsigned short* pA0h = Qhi + (size_t)m0 * ND + kbase + q * 8;
  const unsigned short* pA0l = Qlo + (size_t)m0 * ND + kbase + q * 8;
  const uint4* ASv = (const uint4*)&AS[0][0];   // 16B units: [row*32 + col]

  f32x4 acc[3][2];
#pragma unroll
  for (int mt = 0; mt < 3; ++mt)
#pragma unroll
    for (int nt = 0; nt < 2; ++nt) acc[mt][nt] = (f32x4){0.f, 0.f, 0.f, 0.f};

  bf16x8 qa[2][6];
#pragma unroll
  for (int f = 0; f < 3; ++f) {
    qa[0][2 * f]     = ldg8(pA0h + f * 16 * ND);
    qa[0][2 * f + 1] = ldg8(pA0l + f * 16 * ND);
  }

#pragma unroll
  for (int it = 0; it < 8; ++it) {
    const int cur = it & 1, nxt = cur ^ 1;
    if (it < 7) {
      const int ko = (it + 1) * 32;
#pragma unroll
      for (int f = 0; f < 3; ++f) {
        qa[nxt][2 * f]     = ldg8(pA0h + f * 16 * ND + ko);
        qa[nxt][2 * f + 1] = ldg8(pA0l + f * 16 * ND + ko);
      }
    }
    const int cx = (it * 4 + q) ^ (r16 & 7);   // swizzled 16B col
    bf16x8 b0h = __builtin_bit_cast(bf16x8, ASv[r16 * 32 + cx]);
    bf16x8 b1h = __builtin_bit_cast(bf16x8, ASv[(16 + r16) * 32 + cx]);
    bf16x8 b0l = __builtin_bit_cast(bf16x8, ASv[(32 + r16) * 32 + cx]);
    bf16x8 b1l = __builtin_bit_cast(bf16x8, ASv[(48 + r16) * 32 + cx]);

    acc[0][0] = mfma16(qa[cur][0], b0h, acc[0][0]);
    acc[0][0] = mfma16(qa[cur][1], b0h, acc[0][0]);
    acc[0][0] = mfma16(qa[cur][0], b0l, acc[0][0]);
    acc[1][0] = mfma16(qa[cur][2], b0h, acc[1][0]);
    acc[1][0] = mfma16(qa[cur][3], b0h, acc[1][0]);
    acc[1][0] = mfma16(qa[cur][2], b0l, acc[1][0]);
    acc[2][0] = mfma16(qa[cur][4], b0h, acc[2][0]);
    acc[2][0] = mfma16(qa[cur][5], b0h, acc[2][0]);
    acc[2][0] = mfma16(qa[cur][4], b0l, acc[2][0]);
    acc[0][1] = mfma16(qa[cur][0], b1h, acc[0][1]);
    acc[0][1] = mfma16(qa[cur][1], b1h, acc[0][1]);
    acc[0][1] = mfma16(qa[cur][0], b1l, acc[0][1]);
    acc[1][1] = mfma16(qa[cur][2], b1h, acc[1][1]);
    acc[1][1] = mfma16(qa[cur][3], b1h, acc[1][1]);
    acc[1][1] = mfma16(qa[cur][2], b1l, acc[1][1]);
    acc[2][1] = mfma16(qa[cur][4], b1h, acc[2][1]);
    acc[2][1] = mfma16(qa[cur][5], b1h, acc[2][1]);
    acc[2][1] = mfma16(qa[cur][4], b1l, acc[2][1]);
  }

  float* Pk = P + kc * (MT * ND);
#pragma unroll
  for (int mt = 0; mt < 3; ++mt)
#pragma unroll
    for (int nt = 0; nt < 2; ++nt) {
      int mbase = g * 48 + mt * 16 + q * 4;
      int n = n0 + nt * 16 + r16;
#pragma unroll
      for (int r = 0; r < 4; ++r)
        Pk[(mbase + r) * ND + n] = acc[mt][nt][r];
    }
}

// Sum KS partials, add beta on row 128, write split bf16 (full width).
__global__ __launch_bounds__(256) void reduce_step(
    const float* __restrict__ P, const float* __restrict__ beta,
    unsigned short* __restrict__ Ohi, unsigned short* __restrict__ Olo) {
  int t = blockIdx.x * 256 + threadIdx.x;   // 288*256 = 73728 = MT*ND/4
  int m = t >> 9;
  int n = (t & 511) * 4;
  int idx = m * ND + n;
  const int stride = MT * ND;
  float v0 = 0.f, v1 = 0.f, v2 = 0.f, v3 = 0.f;
#pragma unroll
  for (int c = 0; c < KS; ++c) {
    float4 s = *(const float4*)(P + c * stride + idx);
    v0 += s.x; v1 += s.y; v2 += s.z; v3 += s.w;
  }
  if (m == 128) {
    float4 b4 = *(const float4*)(beta + n);
    v0 += b4.x; v1 += b4.y; v2 += b4.z; v3 += b4.w;
  }
  union { unsigned short u[4]; uint2 d; } h, l;
  float vv[4] = {v0, v1, v2, v3};
#pragma unroll
  for (int i = 0; i < 4; ++i) {
    unsigned short hh = f2bf(vv[i]);
    h.u[i] = hh;
    l.u[i] = f2bf(vv[i] - bf2f(hh));
  }
  *(uint2*)(Ohi + idx) = h.d;
  *(uint2*)(Olo + idx) = l.d;
}

// ---------------------------------------------------------------------------
// Tail (3 wide kernels, fp32-exact S path):
//   extract_Sc: St[d][e] = sum_c P[c][d][1920+e]; c[e] likewise + beta
//   tail_T1g:   T1[e,ic] = sum_d St[d][e]*Wpre[d,ic];  g[e] = c[e]+St[:,e]·bpre
//   tail_Weff:  Weff[o,ic] = sum_e Wpost[o,e]*T1[e,ic] -> split bf16;
//               beff[o] = bpost[o] + Wpost[o,:]·g
// ---------------------------------------------------------------------------
__global__ __launch_bounds__(256) void extract_Sc(
    const float* __restrict__ P, const float* __restrict__ beta,
    float* __restrict__ St, float* __restrict__ gv) {
  int t = blockIdx.x * 256 + threadIdx.x;
  const int PSTR = MT * ND;
  if (t < 16384) {
    int d = t >> 7, e = t & 127;
    float v = 0.f;
#pragma unroll
    for (int c = 0; c < KS; ++c) v += P[c * PSTR + d * ND + 1920 + e];
    St[t] = v;                                   // St[d][e]
  } else if (t < 16512) {
    int e = t - 16384;
    float v = beta[1920 + e];
#pragma unroll
    for (int c = 0; c < KS; ++c) v += P[c * PSTR + 128 * ND + 1920 + e];
    gv[e] = v;
  }
}

__global__ __launch_bounds__(256) void tail_T1g(
    const float* __restrict__ St, const float* __restrict__ Wpre,
    const float* __restrict__ bpre, float* __restrict__ T1,
    float* __restrict__ gv) {
  int t = blockIdx.x * 256 + threadIdx.x;
  if (t < 65536) {
    int e = t >> 9, ic = t & 511;
    float s = 0.f;
    for (int d = 0; d < 128; ++d) s += St[d * 128 + e] * Wpre[d * 512 + ic];
    T1[t] = s;
  } else if (t < 65664) {
    int e = t - 65536;
    float s = gv[e];
    for (int d = 0; d < 128; ++d) s += St[d * 128 + e] * bpre[d];
    gv[e] = s;                                   // only this thread touches e
  }
}

__global__ __launch_bounds__(256) void tail_Weff(
    const float* __restrict__ Wpost, const float* __restrict__ T1,
    const float* __restrict__ gv, const float* __restrict__ bpost,
    unsigned short* __restrict__ Whi, unsigned short* __restrict__ Wlo,
    float* __restrict__ beff) {
  int t = blockIdx.x * 256 + threadIdx.x;
  if (t < 262144) {
    int o = t >> 9, ic = t & 511;
    float s = 0.f;
    for (int e = 0; e < 128; ++e) s += Wpost[o * 128 + e] * T1[e * 512 + ic];
    unsigned short h = f2bf(s);
    Whi[t] = h;
    Wlo[t] = f2bf(s - bf2f(h));
  } else if (t < 262656) {
    int o = t - 262144;
    float s = bpost[o];
    for (int e = 0; e < 128; ++e) s += Wpost[o * 128 + e] * gv[e];
    beff[o] = s;
  }
}

// ---------------------------------------------------------------------------
// out[4096,512] = inp @ Weff^T + beff. M=4096,N=512,K=512, split bf16.
// Block tile 64(M) x 128(N): grid (64,4), 4 waves; wave w owns n-cols [32w,32w+32).
// ---------------------------------------------------------------------------
__global__ __launch_bounds__(256) void final_gemm(
    const unsigned short* __restrict__ Ihi, const unsigned short* __restrict__ Ilo,
    const unsigned short* __restrict__ Whi, const unsigned short* __restrict__ Wlo,
    const float* __restrict__ beff, float* __restrict__ out) {
  __shared__ __align__(16) unsigned short Is_hi[64][40], Is_lo[64][40];
  __shared__ __align__(16) unsigned short Ws_hi[128][40], Ws_lo[128][40];
  const int t = threadIdx.x;
  const int mb = blockIdx.x, nb = blockIdx.y;
  const int w = t >> 6, lane = t & 63;
  const int r16 = lane & 15, q = lane >> 4;

  f32x4 acc[4][2];
#pragma unroll
  for (int x = 0; x < 4; ++x)
#pragma unroll
    for (int b = 0; b < 2; ++b) acc[x][b] = (f32x4){0.f, 0.f, 0.f, 0.f};

  for (int kc = 0; kc < 16; ++kc) {
    const int k0 = kc * 32;
#pragma unroll
    for (int rpt = 0; rpt < 6; ++rpt) {
      int slot = t + rpt * 256;
      if (slot < 512) {
        int arr = slot >> 8, s = slot & 255;
        int row = s >> 2, off = (s & 3) * 8;
        const unsigned short* src = arr ? Ilo : Ihi;
        unsigned short* dst = arr ? &Is_lo[row][off] : &Is_hi[row][off];
        *(uint4*)dst = *(const uint4*)(src + (mb * 64 + row) * 512 + k0 + off);
      } else {
        int s = slot - 512;
        int arr = s >> 9, s2 = s & 511;
        int row = s2 >> 2, off = (s2 & 3) * 8;
        const unsigned short* src = arr ? Wlo : Whi;
        unsigned short* dst = arr ? &Ws_lo[row][off] : &Ws_hi[row][off];
        *(uint4*)dst = *(const uint4*)(src + (nb * 128 + row) * 512 + k0 + off);
      }
    }
    __syncthreads();

    bf16x8 bh0 = __builtin_bit_cast(bf16x8, *(const uint4*)&Ws_hi[w * 32 + r16][q * 8]);
    bf16x8 bl0 = __builtin_bit_cast(bf16x8, *(const uint4*)&Ws_lo[w * 32 + r16][q * 8]);
    bf16x8 bh1 = __builtin_bit_cast(bf16x8, *(const uint4*)&Ws_hi[w * 32 + 16 + r16][q * 8]);
    bf16x8 bl1 = __builtin_bit_cast(bf16x8, *(const uint4*)&Ws_lo[w * 32 + 16 + r16][q * 8]);
#pragma unroll
    for (int mt = 0; mt < 4; ++mt) {
      bf16x8 ah = __builtin_bit_cast(bf16x8, *(const uint4*)&Is_hi[mt * 16 + r16][q * 8]);
      bf16x8 al = __builtin_bit_cast(bf16x8, *(const uint4*)&Is_lo[mt * 16 + r16][q * 8]);
      acc[mt][0] = mfma16(ah, bh0, acc[mt][0]);
      acc[mt][0] = mfma16(al, bh0, acc[mt][0]);
      acc[mt][0] = mfma16(ah, bl0, acc[mt][0]);
      acc[mt][1] = mfma16(ah, bh1, acc[mt][1]);
      acc[mt][1] = mfma16(al, bh1, acc[mt][1]);
      acc[mt][1] = mfma16(ah, bl1, acc[mt][1]);
    }
    __syncthreads();
  }

#pragma unroll
  for (int mt = 0; mt < 4; ++mt)
#pragma unroll
    for (int nt = 0; nt < 2; ++nt) {
      int n = nb * 128 + w * 32 + nt * 16 + r16;
      float bv = beff[n];
#pragma unroll
      for (int r = 0; r < 4; ++r) {
        int m = mb * 64 + mt * 16 + q * 4 + r;
        out[m * 512 + n] = acc[mt][nt][r] + bv;
      }
    }
}

extern "C" void kernel_launch(void* const* d_in, const int* in_sizes, int n_in,
                              void* d_out, int out_size, void* d_ws, size_t ws_size,
                              hipStream_t stream) {
  const float* inp   = (const float*)d_in[0];
  const float* Wpre  = (const float*)d_in[1];
  const float* bpre  = (const float*)d_in[2];
  const float* W     = (const float*)d_in[3];
  const float* bl    = (const float*)d_in[4];
  const float* life  = (const float*)d_in[5];
  const float* Wpost = (const float*)d_in[6];
  const float* bpost = (const float*)d_in[7];
  float* out = (float*)d_out;

  char* p = (char*)d_ws;
  auto alloc = [&](size_t bytes) {
    char* r = p;
    p += (bytes + 255) & ~(size_t)255;
    return r;
  };
  unsigned short* Ahi  = (unsigned short*)alloc((size_t)ND * ND * 2);
  unsigned short* Alo  = (unsigned short*)alloc((size_t)ND * ND * 2);
  unsigned short* QAhi = (unsigned short*)alloc((size_t)MT * ND * 2);
  unsigned short* QAlo = (unsigned short*)alloc((size_t)MT * ND * 2);
  unsigned short* QBhi = (unsigned short*)alloc((size_t)MT * ND * 2);
  unsigned short* QBlo = (unsigned short*)alloc((size_t)MT * ND * 2);
  float* beta = (float*)alloc(ND * 4);
  float* P    = (float*)alloc((size_t)KS * MT * ND * 4);
  float* St   = (float*)alloc(128 * 128 * 4);
  float* gv   = (float*)alloc(128 * 4);
  float* T1   = (float*)alloc(128 * 512 * 4);
  float* beff = (float*)alloc(512 * 4);
  unsigned short* Whi = (unsigned short*)alloc(512 * 512 * 2);
  unsigned short* Wlo = (unsigned short*)alloc(512 * 512 * 2);
  unsigned short* Ihi = (unsigned short*)alloc((size_t)4096 * 512 * 2);
  unsigned short* Ilo = (unsigned short*)alloc((size_t)4096 * 512 * 2);

  build_all<<<1024, 256, 0, stream>>>(W, life, bl, inp, Ahi, Alo, QAhi, QAlo,
                                      beta, Ihi, Ilo);

  // steps t=2..10: 8 full multiplies + 1 restricted to n in [1920,2048)
  const unsigned short *qh = QAhi, *ql = QAlo;
  unsigned short *oh = QBhi, *ol = QBlo;
  for (int i = 1; i <= 9; ++i) {
    if (i < 9) {
      step_kernel<<<dim3(64, KS), 192, 0, stream>>>(Ahi, Alo, qh, ql, P, 0);
      reduce_step<<<288, 256, 0, stream>>>(P, beta, oh, ol);
      const unsigned short* th = qh; qh = oh; oh = (unsigned short*)th;
      const unsigned short* tl = ql; ql = ol; ol = (unsigned short*)tl;
    } else {
      step_kernel<<<dim3(4, KS), 192, 0, stream>>>(Ahi, Alo, qh, ql, P, 60);
    }
  }

  extract_Sc<<<65, 256, 0, stream>>>(P, beta, St, gv);
  tail_T1g<<<257, 256, 0, stream>>>(St, Wpre, bpre, T1, gv);
  tail_Weff<<<1026, 256, 0, stream>>>(Wpost, T1, gv, bpost, Whi, Wlo, beff);
  final_gemm<<<dim3(64, 4), 256, 0, stream>>>(Ihi, Ilo, Whi, Wlo, beff, out);
}